// Round 3
// baseline (1324.128 us; speedup 1.0000x reference)
//
#include <hip/hip_runtime.h>
#include <hip/hip_bf16.h>

// Qwen3 MoE block: T=8192 tokens, H=1024, I=512, E=32, top-4.
// v3: FUSED expert MLP. ws usage capped at ~525 KB (control data only) —
// round-2 post-timing failure was traced to 32MB hbuf writes at ws+1MiB
// overrunning a small ws allocation and corrupting harness pristine buffers.
// Per block (64 expert-slots): gate/up GEMM (K=1024, fp32->bf16 on the fly)
// -> h[64][512] bf16 in LDS -> down GEMM (K=512, A from LDS) -> fp32
// atomicAdd into zeroed d_out.

#define T_TOK 8192
#define H_DIM 1024
#define I_DIM 512
#define E_NUM 32
#define K_TOP 4
#define NSLOT (T_TOK * K_TOP)

typedef __bf16 bf16_t;
typedef __bf16 bf16x8 __attribute__((ext_vector_type(8)));
typedef float floatx4 __attribute__((ext_vector_type(4)));

// 16B-chunk XOR swizzle within 64B (32-elem bf16) LDS rows
#define SWZ(r) (((r) >> 2) & 3)

__device__ __forceinline__ bf16x8 cvt8(float4 a, float4 b) {
  bf16x8 o;
  o[0] = (bf16_t)a.x; o[1] = (bf16_t)a.y;
  o[2] = (bf16_t)a.z; o[3] = (bf16_t)a.w;
  o[4] = (bf16_t)b.x; o[5] = (bf16_t)b.y;
  o[6] = (bf16_t)b.z; o[7] = (bf16_t)b.w;
  return o;
}

// ---------------- Router: one block per token ----------------
__global__ __launch_bounds__(256) void router_kernel(
    const float* __restrict__ x, const float* __restrict__ gate_w,
    int* __restrict__ counts, int* __restrict__ topk_idx,
    float* __restrict__ topk_wt) {
  __shared__ float sx[H_DIM];
  __shared__ float slog[E_NUM];
  int t = blockIdx.x;
  const float* xr = x + (size_t)t * H_DIM;
  for (int i = threadIdx.x; i < H_DIM / 4; i += 256)
    ((float4*)sx)[i] = ((const float4*)xr)[i];
  __syncthreads();

  int e = threadIdx.x >> 3;  // 32 experts x 8 threads
  int p = threadIdx.x & 7;
  const float* gw = gate_w + (size_t)e * H_DIM;
  float acc = 0.f;
  for (int h = p; h < H_DIM; h += 8) acc += sx[h] * gw[h];
  acc += __shfl_xor(acc, 1);
  acc += __shfl_xor(acc, 2);
  acc += __shfl_xor(acc, 4);
  if (p == 0) slog[e] = acc;
  __syncthreads();

  if (threadIdx.x == 0) {
    float v[E_NUM];
    for (int i = 0; i < E_NUM; i++) v[i] = slog[i];
    int idx[K_TOP];
    float val[K_TOP];
    for (int k = 0; k < K_TOP; k++) {
      int bi = 0;
      float bv = -1e30f;
      for (int i = 0; i < E_NUM; i++)
        if (v[i] > bv) { bv = v[i]; bi = i; }
      idx[k] = bi; val[k] = bv; v[bi] = -1e30f;
    }
    // softmax denominator cancels under top-k renorm
    float m = val[0], s = 0.f, w[K_TOP];
    for (int k = 0; k < K_TOP; k++) { w[k] = __expf(val[k] - m); s += w[k]; }
    float inv = 1.f / s;
    for (int k = 0; k < K_TOP; k++) {
      topk_idx[t * K_TOP + k] = idx[k];
      topk_wt[t * K_TOP + k] = w[k] * inv;
      atomicAdd(&counts[idx[k]], 1);
    }
  }
}

__global__ void scan_kernel(const int* __restrict__ counts,
                            int* __restrict__ offsets) {
  if (threadIdx.x == 0 && blockIdx.x == 0) {
    int acc = 0;
    for (int e = 0; e < E_NUM; e++) { offsets[e] = acc; acc += counts[e]; }
    offsets[E_NUM] = acc;
  }
}

__global__ __launch_bounds__(256) void build_kernel(
    const int* __restrict__ topk_idx, const float* __restrict__ topk_wt,
    const int* __restrict__ offsets, int* __restrict__ cursors,
    int* __restrict__ token_list, float* __restrict__ slot_wt) {
  int t = blockIdx.x * 256 + threadIdx.x;
  if (t >= T_TOK) return;
  for (int k = 0; k < K_TOP; k++) {
    int e = topk_idx[t * K_TOP + k];
    int pos = atomicAdd(&cursors[e], 1);
    int slot = offsets[e] + pos;
    token_list[slot] = t;
    slot_wt[slot] = topk_wt[t * K_TOP + k];
  }
}

// ---------------- fused expert MLP ----------------
// grid (T_TOK/64, 1, E), 256 threads. LDS: h 64KB + staging 12KB (~78KB,
// 2 blocks/CU). Phase 1: gate/up, n-chunks of 64 over I, BK=32.
// Phase 2: down, n-chunks of 128 over H, K=512 with A straight from LDS-h.
__global__ __launch_bounds__(256) void fusedC_kernel(
    const float* __restrict__ x, const float* __restrict__ w_gate,
    const float* __restrict__ w_up, const float* __restrict__ w_down,
    const int* __restrict__ counts, const int* __restrict__ offsets,
    const int* __restrict__ token_list, const float* __restrict__ slot_wt,
    float* __restrict__ out) {
  int e = blockIdx.z;
  int cnt = counts[e];
  int m_base = blockIdx.x * 64;
  if (m_base >= cnt) return;
  int off = offsets[e];

  __shared__ __align__(16) bf16_t sH[64 * 512];     // h, chunk-xor swizzled
  __shared__ __align__(16) bf16_t sStage[3 * 2048]; // p1: A|Bg|Bu, p2: Bd
  __shared__ float sW[64];
  __shared__ int sTok[64];

  int tid = threadIdx.x;
  if (tid < 64) {
    int s = m_base + tid;
    bool v = (s < cnt);
    sTok[tid] = v ? token_list[off + s] : token_list[off];
    sW[tid] = v ? slot_wt[off + s] : 0.f;
  }
  __syncthreads();

  int lane = tid & 63, w = tid >> 6;
  int l15 = lane & 15, q = lane >> 4;

  // ---- phase-1 staging roles ----
  int arow = tid >> 2, acq = tid & 3;     // A: 64 rows x 4 chunks
  int tokA = sTok[arow];
  const float* gA = x + (size_t)tokA * H_DIM + acq * 8;
  bf16_t* lA = sStage + arow * 32 + ((acq ^ SWZ(arow)) * 8);
  int brow = tid & 63, bcq = tid >> 6;    // B: 64 n-rows x 4 chunks
  const float* gBg =
      w_gate + (size_t)e * H_DIM * I_DIM + (size_t)(bcq * 8) * I_DIM + brow;
  const float* gBu =
      w_up + (size_t)e * H_DIM * I_DIM + (size_t)(bcq * 8) * I_DIM + brow;
  bf16_t* lBg = sStage + 2048 + brow * 32 + ((bcq ^ SWZ(brow)) * 8);
  bf16_t* lBu = sStage + 4096 + brow * 32 + ((bcq ^ SWZ(brow)) * 8);

  // ---- phase-1 fragment offsets (wave tiles 32x32 of the 64x64 tile) ----
  int wm = (w >> 1) * 32, wn = (w & 1) * 32;
  int aoff[2], boff[2];
#pragma unroll
  for (int mi = 0; mi < 2; mi++) {
    int r = wm + mi * 16 + l15;
    aoff[mi] = r * 32 + ((q ^ SWZ(r)) * 8);
  }
#pragma unroll
  for (int ni = 0; ni < 2; ni++) {
    int r = wn + ni * 16 + l15;
    boff[ni] = r * 32 + ((q ^ SWZ(r)) * 8);
  }

  floatx4 zero = {0.f, 0.f, 0.f, 0.f};

  // =================== phase 1: h = silu(x Wg) * (x Wu) ===================
  for (int nc = 0; nc < I_DIM; nc += 64) {
    floatx4 ag[2][2], au[2][2];
#pragma unroll
    for (int mi = 0; mi < 2; mi++)
#pragma unroll
      for (int ni = 0; ni < 2; ni++) { ag[mi][ni] = zero; au[mi][ni] = zero; }

    for (int k0 = 0; k0 < H_DIM; k0 += 32) {
      // stage A (x, gathered rows): 8 contiguous fp32 -> bf16x8
      float4 a0 = *(const float4*)(gA + k0);
      float4 a1 = *(const float4*)(gA + k0 + 4);
      *(bf16x8*)lA = cvt8(a0, a1);
      // stage Bg/Bu: 8 k-strided fp32 each (lanes coalesce along n)
      const float* pg = gBg + (size_t)k0 * I_DIM + nc;
      const float* pu = gBu + (size_t)k0 * I_DIM + nc;
      bf16x8 bgv, buv;
#pragma unroll
      for (int j = 0; j < 8; j++) {
        bgv[j] = (bf16_t)pg[(size_t)j * I_DIM];
        buv[j] = (bf16_t)pu[(size_t)j * I_DIM];
      }
      *(bf16x8*)lBg = bgv;
      *(bf16x8*)lBu = buv;
      __syncthreads();

      bf16x8 af[2], bg[2], bu[2];
#pragma unroll
      for (int mi = 0; mi < 2; mi++) af[mi] = *(const bf16x8*)&sStage[aoff[mi]];
#pragma unroll
      for (int ni = 0; ni < 2; ni++) {
        bg[ni] = *(const bf16x8*)&sStage[2048 + boff[ni]];
        bu[ni] = *(const bf16x8*)&sStage[4096 + boff[ni]];
      }
#pragma unroll
      for (int mi = 0; mi < 2; mi++)
#pragma unroll
        for (int ni = 0; ni < 2; ni++) {
          ag[mi][ni] = __builtin_amdgcn_mfma_f32_16x16x32_bf16(
              af[mi], bg[ni], ag[mi][ni], 0, 0, 0);
          au[mi][ni] = __builtin_amdgcn_mfma_f32_16x16x32_bf16(
              af[mi], bu[ni], au[mi][ni], 0, 0, 0);
        }
      __syncthreads();
    }

    // epilogue: silu(g)*u -> sH (chunk-xor swizzle: c' = (col>>3) ^ (row&7))
#pragma unroll
    for (int mi = 0; mi < 2; mi++)
#pragma unroll
      for (int ni = 0; ni < 2; ni++)
#pragma unroll
        for (int r = 0; r < 4; r++) {
          int row = wm + mi * 16 + q * 4 + r;
          int col = nc + wn + ni * 16 + l15;
          float g = ag[mi][ni][r];
          float u = au[mi][ni][r];
          float hv = g * (1.f / (1.f + __expf(-g))) * u;
          sH[row * 512 + ((((col >> 3) ^ (row & 7)) << 3) + (col & 7))] =
              (bf16_t)hv;
        }
  }
  __syncthreads();  // h complete before phase 2 overwrites sStage

  // =================== phase 2: y += w * (h Wd) ===================
  int b2row = tid & 127, b2grp = (tid >> 7) * 2;  // 128 n-rows x 4 chunks, 2/thr
  const float* gBd = w_down + (size_t)e * I_DIM * H_DIM + b2row;
  bf16_t* lBd0 = sStage + b2row * 32 + (((b2grp + 0) ^ SWZ(b2row)) * 8);
  bf16_t* lBd1 = sStage + b2row * 32 + (((b2grp + 1) ^ SWZ(b2row)) * 8);

  int wm2 = (w >> 1) * 32, wn2 = (w & 1) * 64;
  int a2base[2], a2x[2];
#pragma unroll
  for (int mi = 0; mi < 2; mi++) {
    int m = wm2 + mi * 16 + l15;
    a2base[mi] = m * 512;
    a2x[mi] = m & 7;
  }
  int b2off[4];
#pragma unroll
  for (int ni = 0; ni < 4; ni++) {
    int r = wn2 + ni * 16 + l15;
    b2off[ni] = r * 32 + ((q ^ SWZ(r)) * 8);
  }

  for (int nb2 = 0; nb2 < H_DIM; nb2 += 128) {
    floatx4 acc[2][4];
#pragma unroll
    for (int mi = 0; mi < 2; mi++)
#pragma unroll
      for (int ni = 0; ni < 4; ni++) acc[mi][ni] = zero;

    for (int k0 = 0; k0 < I_DIM; k0 += 32) {
      const float* p0 = gBd + (size_t)(k0 + (b2grp + 0) * 8) * H_DIM + nb2;
      const float* p1 = gBd + (size_t)(k0 + (b2grp + 1) * 8) * H_DIM + nb2;
      bf16x8 b0, b1;
#pragma unroll
      for (int j = 0; j < 8; j++) {
        b0[j] = (bf16_t)p0[(size_t)j * H_DIM];
        b1[j] = (bf16_t)p1[(size_t)j * H_DIM];
      }
      *(bf16x8*)lBd0 = b0;
      *(bf16x8*)lBd1 = b1;
      __syncthreads();

      bf16x8 af2[2], bf2[4];
#pragma unroll
      for (int mi = 0; mi < 2; mi++)
        af2[mi] = *(const bf16x8*)
            &sH[a2base[mi] + ((((k0 >> 3) + q) ^ a2x[mi]) * 8)];
#pragma unroll
      for (int ni = 0; ni < 4; ni++)
        bf2[ni] = *(const bf16x8*)&sStage[b2off[ni]];
#pragma unroll
      for (int mi = 0; mi < 2; mi++)
#pragma unroll
        for (int ni = 0; ni < 4; ni++)
          acc[mi][ni] = __builtin_amdgcn_mfma_f32_16x16x32_bf16(
              af2[mi], bf2[ni], acc[mi][ni], 0, 0, 0);
      __syncthreads();
    }

    // epilogue: fp32 atomics into zeroed out
#pragma unroll
    for (int mi = 0; mi < 2; mi++)
#pragma unroll
      for (int ni = 0; ni < 4; ni++)
#pragma unroll
        for (int r = 0; r < 4; r++) {
          int row = wm2 + mi * 16 + q * 4 + r;
          int col = nb2 + wn2 + ni * 16 + l15;
          if (m_base + row < cnt) {
            atomicAdd(&out[(size_t)sTok[row] * H_DIM + col],
                      acc[mi][ni][r] * sW[row]);
          }
        }
  }
}

// ===========================================================================
extern "C" void kernel_launch(void* const* d_in, const int* in_sizes, int n_in,
                              void* d_out, int out_size, void* d_ws,
                              size_t ws_size, hipStream_t stream) {
  const float* x = (const float*)d_in[0];
  const float* gate_w = (const float*)d_in[1];
  const float* w_gate = (const float*)d_in[2];
  const float* w_up = (const float*)d_in[3];
  const float* w_down = (const float*)d_in[4];
  float* out = (float*)d_out;

  // ws usage: 512 B control + 4x128KB arrays = ~525 KB total. Nothing else.
  char* ws = (char*)d_ws;
  int* counts = (int*)(ws + 0);
  int* cursors = (int*)(ws + 128);
  int* offsets = (int*)(ws + 256);
  int* topk_idx = (int*)(ws + 512);
  float* topk_wt = (float*)(ws + 512 + 131072);
  int* token_list = (int*)(ws + 512 + 2 * 131072);
  float* slot_wt = (float*)(ws + 512 + 3 * 131072);

  hipMemsetAsync(ws, 0, 512, stream);
  hipMemsetAsync(out, 0, (size_t)out_size * sizeof(float), stream);
  router_kernel<<<T_TOK, 256, 0, stream>>>(x, gate_w, counts, topk_idx,
                                           topk_wt);
  scan_kernel<<<1, 64, 0, stream>>>(counts, offsets);
  build_kernel<<<T_TOK / 256, 256, 0, stream>>>(topk_idx, topk_wt, offsets,
                                                cursors, token_list, slot_wt);
  fusedC_kernel<<<dim3(T_TOK / 64, 1, E_NUM), 256, 0, stream>>>(
      x, w_gate, w_up, w_down, counts, offsets, token_list, slot_wt, out);
}

// Round 4
// 1198.454 us; speedup vs baseline: 1.1049x; 1.1049x over previous
//
#include <hip/hip_runtime.h>
#include <hip/hip_bf16.h>

// Qwen3 MoE block: T=8192 tokens, H=1024, I=512, E=32, top-4.
// v4: fused expert MLP (ws ~525 KB only). vs v3:
//  - weight staging via coalesced dwordx4 k-pair loads + in-register bf16
//    pack + b32 LDS writes (VMEM instrs per k-step: 18 -> 6 / 16 -> 4)
//  - register double-buffer: next k-step's global loads issued before MFMA
//  - XCD-pinned expert swizzle: all blocks of an expert share one XCD's L2
//  - router: float4 dot + wave-parallel top-k

#define T_TOK 8192
#define H_DIM 1024
#define I_DIM 512
#define E_NUM 32
#define K_TOP 4
#define NSLOT (T_TOK * K_TOP)

typedef __bf16 bf16_t;
typedef __bf16 bf16x2 __attribute__((ext_vector_type(2)));
typedef __bf16 bf16x8 __attribute__((ext_vector_type(8)));
typedef float floatx4 __attribute__((ext_vector_type(4)));

// 16B-chunk XOR swizzle within 64B (32-elem bf16) LDS rows
#define SWZ(r) (((r) >> 2) & 3)

__device__ __forceinline__ bf16x8 cvt8(float4 a, float4 b) {
  bf16x8 o;
  o[0] = (bf16_t)a.x; o[1] = (bf16_t)a.y;
  o[2] = (bf16_t)a.z; o[3] = (bf16_t)a.w;
  o[4] = (bf16_t)b.x; o[5] = (bf16_t)b.y;
  o[6] = (bf16_t)b.z; o[7] = (bf16_t)b.w;
  return o;
}

// ---------------- Router ----------------
__global__ __launch_bounds__(256) void router_kernel(
    const float* __restrict__ x, const float* __restrict__ gate_w,
    int* __restrict__ counts, int* __restrict__ topk_idx,
    float* __restrict__ topk_wt) {
  __shared__ float sx[H_DIM];
  __shared__ float slog[E_NUM];
  int t = blockIdx.x;
  const float* xr = x + (size_t)t * H_DIM;
  for (int i = threadIdx.x; i < H_DIM / 4; i += 256)
    ((float4*)sx)[i] = ((const float4*)xr)[i];
  __syncthreads();

  int e = threadIdx.x >> 3;  // 32 experts x 8 threads
  int p = threadIdx.x & 7;
  const float4* gw4 = (const float4*)(gate_w + (size_t)e * H_DIM);
  const float4* sx4 = (const float4*)sx;
  float acc = 0.f;
  for (int h4 = p; h4 < H_DIM / 4; h4 += 8) {
    float4 w = gw4[h4];
    float4 xv = sx4[h4];
    acc += w.x * xv.x + w.y * xv.y + w.z * xv.z + w.w * xv.w;
  }
  acc += __shfl_xor(acc, 1);
  acc += __shfl_xor(acc, 2);
  acc += __shfl_xor(acc, 4);
  if (p == 0) slog[e] = acc;
  __syncthreads();

  if (threadIdx.x < 64) {
    int lane = threadIdx.x;
    float vv = (lane < E_NUM) ? slog[lane] : -1e30f;
    float val[K_TOP];
    int idx[K_TOP];
#pragma unroll
    for (int k = 0; k < K_TOP; k++) {
      float bv = vv;
      int bi = lane;
#pragma unroll
      for (int d = 1; d < 64; d <<= 1) {
        float ov = __shfl_xor(bv, d);
        int oi = __shfl_xor(bi, d);
        if (ov > bv || (ov == bv && oi < bi)) { bv = ov; bi = oi; }
      }
      val[k] = bv; idx[k] = bi;
      if (lane == bi) vv = -1e30f;
    }
    if (lane == 0) {
      // softmax denominator cancels under top-k renorm
      float m = val[0], s = 0.f, w[K_TOP];
#pragma unroll
      for (int k = 0; k < K_TOP; k++) { w[k] = __expf(val[k] - m); s += w[k]; }
      float inv = 1.f / s;
#pragma unroll
      for (int k = 0; k < K_TOP; k++) {
        topk_idx[t * K_TOP + k] = idx[k];
        topk_wt[t * K_TOP + k] = w[k] * inv;
        atomicAdd(&counts[idx[k]], 1);
      }
    }
  }
}

__global__ void scan_kernel(const int* __restrict__ counts,
                            int* __restrict__ offsets) {
  if (threadIdx.x == 0 && blockIdx.x == 0) {
    int acc = 0;
    for (int e = 0; e < E_NUM; e++) { offsets[e] = acc; acc += counts[e]; }
    offsets[E_NUM] = acc;
  }
}

__global__ __launch_bounds__(256) void build_kernel(
    const int* __restrict__ topk_idx, const float* __restrict__ topk_wt,
    const int* __restrict__ offsets, int* __restrict__ cursors,
    int* __restrict__ token_list, float* __restrict__ slot_wt) {
  int t = blockIdx.x * 256 + threadIdx.x;
  if (t >= T_TOK) return;
  for (int k = 0; k < K_TOP; k++) {
    int e = topk_idx[t * K_TOP + k];
    int pos = atomicAdd(&cursors[e], 1);
    int slot = offsets[e] + pos;
    token_list[slot] = t;
    slot_wt[slot] = topk_wt[t * K_TOP + k];
  }
}

// ---------------- fused expert MLP v4 ----------------
__global__ __launch_bounds__(256) void fusedD_kernel(
    const float* __restrict__ x, const float* __restrict__ w_gate,
    const float* __restrict__ w_up, const float* __restrict__ w_down,
    const int* __restrict__ counts, const int* __restrict__ offsets,
    const int* __restrict__ token_list, const float* __restrict__ slot_wt,
    float* __restrict__ out) {
  // XCD-pinned expert swizzle: linear id mod 8 selects expert group so all
  // blocks of one expert land on one XCD (round-robin dispatch heuristic).
  int lin = blockIdx.x + (T_TOK / 64) * blockIdx.z;  // [0, 4096)
  int e = (lin & 7) + 8 * (lin >> 10);
  int m_tile = (lin & 1023) >> 3;
  int cnt = counts[e];
  int m_base = m_tile * 64;
  if (m_base >= cnt) return;
  int off = offsets[e];

  __shared__ __align__(16) bf16_t sH[64 * 512];      // h, chunk-xor swizzled
  __shared__ __align__(16) bf16_t sStage[3 * 2048];  // p1: A|Bg|Bu, p2: Bd
  __shared__ float sW[64];
  __shared__ int sTok[64];

  int tid = threadIdx.x;
  if (tid < 64) {
    int s = m_base + tid;
    bool v = (s < cnt);
    sTok[tid] = v ? token_list[off + s] : token_list[off];
    sW[tid] = v ? slot_wt[off + s] : 0.f;
  }
  __syncthreads();

  int lane = tid & 63, w = tid >> 6;
  int l15 = lane & 15, q = lane >> 4;

  // ---- phase-1 staging roles ----
  int arow = tid >> 2, acq = tid & 3;  // A: 64 rows x 4 chunks of 8
  const float* gA = x + (size_t)sTok[arow] * H_DIM + acq * 8;
  bf16_t* lA = sStage + arow * 32 + ((acq ^ SWZ(arow)) * 8);

  int bkq = tid >> 4;        // 0..15 -> k-pair rows (2bkq, 2bkq+1)
  int bnq = (tid & 15) * 4;  // n quad
  const float* wge = w_gate + (size_t)e * H_DIM * I_DIM;
  const float* wue = w_up + (size_t)e * H_DIM * I_DIM;
  // LDS b32 write slots for the 4 n's (pair index bkq, chunk-xor by n)
  int bws[4];
#pragma unroll
  for (int j = 0; j < 4; j++) {
    int n = bnq + j;
    int pp = (bkq & 3) | (((bkq >> 2) ^ SWZ(n)) << 2);
    bws[j] = n * 32 + pp * 2;  // bf16-elem offset, b32-aligned
  }

  // ---- phase-1 fragment offsets (wave tile 32x32 of 64x64) ----
  int wm = (w >> 1) * 32, wn = (w & 1) * 32;
  int aoff[2], boff[2];
#pragma unroll
  for (int mi = 0; mi < 2; mi++) {
    int r = wm + mi * 16 + l15;
    aoff[mi] = r * 32 + ((q ^ SWZ(r)) * 8);
  }
#pragma unroll
  for (int ni = 0; ni < 2; ni++) {
    int r = wn + ni * 16 + l15;
    boff[ni] = r * 32 + ((q ^ SWZ(r)) * 8);
  }

  floatx4 zero = {0.f, 0.f, 0.f, 0.f};

  // =================== phase 1: h = silu(x Wg) * (x Wu) ===================
  for (int nc = 0; nc < I_DIM; nc += 64) {
    floatx4 ag[2][2], au[2][2];
#pragma unroll
    for (int mi = 0; mi < 2; mi++)
#pragma unroll
      for (int ni = 0; ni < 2; ni++) { ag[mi][ni] = zero; au[mi][ni] = zero; }

    // preload k0 = 0
    const float* pgr = wge + (size_t)(2 * bkq) * I_DIM + nc + bnq;
    const float* pur = wue + (size_t)(2 * bkq) * I_DIM + nc + bnq;
    float4 a0 = *(const float4*)(gA);
    float4 a1 = *(const float4*)(gA + 4);
    float4 g0 = *(const float4*)pgr;
    float4 g1 = *(const float4*)(pgr + I_DIM);
    float4 u0 = *(const float4*)pur;
    float4 u1 = *(const float4*)(pur + I_DIM);

    for (int k0 = 0; k0 < H_DIM; k0 += 32) {
      __syncthreads();
      *(bf16x8*)lA = cvt8(a0, a1);
      {
        float gv0[4] = {g0.x, g0.y, g0.z, g0.w};
        float gv1[4] = {g1.x, g1.y, g1.z, g1.w};
        float uv0[4] = {u0.x, u0.y, u0.z, u0.w};
        float uv1[4] = {u1.x, u1.y, u1.z, u1.w};
#pragma unroll
        for (int j = 0; j < 4; j++) {
          bf16x2 pg2, pu2;
          pg2[0] = (bf16_t)gv0[j]; pg2[1] = (bf16_t)gv1[j];
          pu2[0] = (bf16_t)uv0[j]; pu2[1] = (bf16_t)uv1[j];
          *(bf16x2*)&sStage[2048 + bws[j]] = pg2;
          *(bf16x2*)&sStage[4096 + bws[j]] = pu2;
        }
      }
      __syncthreads();
      if (k0 + 32 < H_DIM) {
        pgr += 32 * I_DIM;
        pur += 32 * I_DIM;
        a0 = *(const float4*)(gA + k0 + 32);
        a1 = *(const float4*)(gA + k0 + 36);
        g0 = *(const float4*)pgr;
        g1 = *(const float4*)(pgr + I_DIM);
        u0 = *(const float4*)pur;
        u1 = *(const float4*)(pur + I_DIM);
      }
      bf16x8 af[2], bg[2], bu[2];
#pragma unroll
      for (int mi = 0; mi < 2; mi++) af[mi] = *(const bf16x8*)&sStage[aoff[mi]];
#pragma unroll
      for (int ni = 0; ni < 2; ni++) {
        bg[ni] = *(const bf16x8*)&sStage[2048 + boff[ni]];
        bu[ni] = *(const bf16x8*)&sStage[4096 + boff[ni]];
      }
#pragma unroll
      for (int mi = 0; mi < 2; mi++)
#pragma unroll
        for (int ni = 0; ni < 2; ni++) {
          ag[mi][ni] = __builtin_amdgcn_mfma_f32_16x16x32_bf16(
              af[mi], bg[ni], ag[mi][ni], 0, 0, 0);
          au[mi][ni] = __builtin_amdgcn_mfma_f32_16x16x32_bf16(
              af[mi], bu[ni], au[mi][ni], 0, 0, 0);
        }
    }

    // epilogue: silu(g)*u -> sH (chunk-xor: c' = (col>>3) ^ (row&7))
#pragma unroll
    for (int mi = 0; mi < 2; mi++)
#pragma unroll
      for (int ni = 0; ni < 2; ni++)
#pragma unroll
        for (int r = 0; r < 4; r++) {
          int row = wm + mi * 16 + q * 4 + r;
          int col = nc + wn + ni * 16 + l15;
          float g = ag[mi][ni][r];
          float u = au[mi][ni][r];
          float hv = g * (1.f / (1.f + __expf(-g))) * u;
          sH[row * 512 + ((((col >> 3) ^ (row & 7)) << 3) + (col & 7))] =
              (bf16_t)hv;
        }
  }
  __syncthreads();

  // =================== phase 2: y += w * (h Wd) ===================
  int b2nq = (tid & 31) * 4;  // n quad within 128
  int b2kq = tid >> 5;        // 0..7 -> pairs b2kq and b2kq+8
  const float* wde = w_down + (size_t)e * I_DIM * H_DIM;
  int b2ws0[4], b2ws1[4];
#pragma unroll
  for (int j = 0; j < 4; j++) {
    int n = b2nq + j;
    int p0 = b2kq, p1 = b2kq + 8;
    int pp0 = (p0 & 3) | (((p0 >> 2) ^ SWZ(n)) << 2);
    int pp1 = (p1 & 3) | (((p1 >> 2) ^ SWZ(n)) << 2);
    b2ws0[j] = n * 32 + pp0 * 2;
    b2ws1[j] = n * 32 + pp1 * 2;
  }

  int wm2 = (w >> 1) * 32, wn2 = (w & 1) * 64;
  int a2base[2], a2x[2];
#pragma unroll
  for (int mi = 0; mi < 2; mi++) {
    int m = wm2 + mi * 16 + l15;
    a2base[mi] = m * 512;
    a2x[mi] = m & 7;
  }
  int b2off[4];
#pragma unroll
  for (int ni = 0; ni < 4; ni++) {
    int r = wn2 + ni * 16 + l15;
    b2off[ni] = r * 32 + ((q ^ SWZ(r)) * 8);
  }

  for (int nb2 = 0; nb2 < H_DIM; nb2 += 128) {
    floatx4 acc[2][4];
#pragma unroll
    for (int mi = 0; mi < 2; mi++)
#pragma unroll
      for (int ni = 0; ni < 4; ni++) acc[mi][ni] = zero;

    // preload k0 = 0: rows 2b2kq, 2b2kq+1, 2b2kq+16, 2b2kq+17
    const float* pdr = wde + (size_t)(2 * b2kq) * H_DIM + nb2 + b2nq;
    float4 d0 = *(const float4*)pdr;
    float4 d1 = *(const float4*)(pdr + H_DIM);
    float4 d2 = *(const float4*)(pdr + 16 * H_DIM);
    float4 d3 = *(const float4*)(pdr + 17 * H_DIM);

    for (int k0 = 0; k0 < I_DIM; k0 += 32) {
      __syncthreads();
      {
        float v0[4] = {d0.x, d0.y, d0.z, d0.w};
        float v1[4] = {d1.x, d1.y, d1.z, d1.w};
        float v2[4] = {d2.x, d2.y, d2.z, d2.w};
        float v3[4] = {d3.x, d3.y, d3.z, d3.w};
#pragma unroll
        for (int j = 0; j < 4; j++) {
          bf16x2 pa, pb;
          pa[0] = (bf16_t)v0[j]; pa[1] = (bf16_t)v1[j];
          pb[0] = (bf16_t)v2[j]; pb[1] = (bf16_t)v3[j];
          *(bf16x2*)&sStage[b2ws0[j]] = pa;
          *(bf16x2*)&sStage[b2ws1[j]] = pb;
        }
      }
      __syncthreads();
      if (k0 + 32 < I_DIM) {
        pdr += 32 * H_DIM;
        d0 = *(const float4*)pdr;
        d1 = *(const float4*)(pdr + H_DIM);
        d2 = *(const float4*)(pdr + 16 * H_DIM);
        d3 = *(const float4*)(pdr + 17 * H_DIM);
      }
      bf16x8 af2[2], bf2[4];
#pragma unroll
      for (int mi = 0; mi < 2; mi++)
        af2[mi] = *(const bf16x8*)
            &sH[a2base[mi] + ((((k0 >> 3) + q) ^ a2x[mi]) * 8)];
#pragma unroll
      for (int ni = 0; ni < 4; ni++)
        bf2[ni] = *(const bf16x8*)&sStage[b2off[ni]];
#pragma unroll
      for (int mi = 0; mi < 2; mi++)
#pragma unroll
        for (int ni = 0; ni < 4; ni++)
          acc[mi][ni] = __builtin_amdgcn_mfma_f32_16x16x32_bf16(
              af2[mi], bf2[ni], acc[mi][ni], 0, 0, 0);
    }

    // epilogue: fp32 atomics into zeroed out
#pragma unroll
    for (int mi = 0; mi < 2; mi++)
#pragma unroll
      for (int ni = 0; ni < 4; ni++)
#pragma unroll
        for (int r = 0; r < 4; r++) {
          int row = wm2 + mi * 16 + q * 4 + r;
          int col = nb2 + wn2 + ni * 16 + l15;
          if (m_base + row < cnt) {
            atomicAdd(&out[(size_t)sTok[row] * H_DIM + col],
                      acc[mi][ni][r] * sW[row]);
          }
        }
  }
}

// ===========================================================================
extern "C" void kernel_launch(void* const* d_in, const int* in_sizes, int n_in,
                              void* d_out, int out_size, void* d_ws,
                              size_t ws_size, hipStream_t stream) {
  const float* x = (const float*)d_in[0];
  const float* gate_w = (const float*)d_in[1];
  const float* w_gate = (const float*)d_in[2];
  const float* w_up = (const float*)d_in[3];
  const float* w_down = (const float*)d_in[4];
  float* out = (float*)d_out;

  // ws usage: 512 B control + 4x128KB arrays = ~525 KB total.
  char* ws = (char*)d_ws;
  int* counts = (int*)(ws + 0);
  int* cursors = (int*)(ws + 128);
  int* offsets = (int*)(ws + 256);
  int* topk_idx = (int*)(ws + 512);
  float* topk_wt = (float*)(ws + 512 + 131072);
  int* token_list = (int*)(ws + 512 + 2 * 131072);
  float* slot_wt = (float*)(ws + 512 + 3 * 131072);

  hipMemsetAsync(ws, 0, 512, stream);
  hipMemsetAsync(out, 0, (size_t)out_size * sizeof(float), stream);
  router_kernel<<<T_TOK, 256, 0, stream>>>(x, gate_w, counts, topk_idx,
                                           topk_wt);
  scan_kernel<<<1, 64, 0, stream>>>(counts, offsets);
  build_kernel<<<T_TOK / 256, 256, 0, stream>>>(topk_idx, topk_wt, offsets,
                                                cursors, token_list, slot_wt);
  fusedD_kernel<<<dim3(T_TOK / 64, 1, E_NUM), 256, 0, stream>>>(
      x, w_gate, w_up, w_down, counts, offsets, token_list, slot_wt, out);
}